// Round 4
// baseline (1211.272 us; speedup 1.0000x reference)
//
#include <hip/hip_runtime.h>
#include <utility>
#include <cstddef>

// GMM E-step: N=200000 points, K=16 components, D=64 dims, fp32.
// R4: precompute reverted to the R1-proven LDS structure (the R2/R3
// register-resident full-unroll is the prime suspect for the build
// failures) with 8-way partial sums to break serial LDS chains.
// estep: column-major Mahalanobis (z-accumulators live in VGPRs --
// non-rematerializable, unlike R1's x[] which the compiler re-fetched
// per FMA at VGPR_Count=36 / VALUBusy 38%), x staged in LDS, K split
// across the 4 waves of a block (R1 was grid-capped at 36% occupancy).

#define GMM_D 64
#define GMM_K 16
#define GMM_TRI 2080  // 64*65/2

// ---------------------------------------------------------------------------
// Precompute: one block (64 threads = 1 wave) per component. R1 structure.
// ---------------------------------------------------------------------------
__global__ __launch_bounds__(64) void gmm_precompute_kernel(
    const float* __restrict__ pi, const float* __restrict__ mus,
    const float* __restrict__ covs, float* __restrict__ Wp,
    float* __restrict__ tv, float* __restrict__ cc)
{
    const int k = blockIdx.x;
    const int i = threadIdx.x;  // row (Cholesky) / column (inverse)

    __shared__ float L[GMM_D][GMM_D + 1];
    __shared__ float Ws[GMM_D][GMM_D + 1];

    for (int j = 0; j < GMM_D; ++j) L[i][j] = covs[k * GMM_D * GMM_D + i * GMM_D + j];
    __syncthreads();

    // Cholesky, column by column; lane i owns row i. 8 partial sums break
    // the serial load->fma->load chain (was ~130cyc per inner iteration).
    for (int j = 0; j < GMM_D; ++j) {
        float s = L[i][j];
        float s0 = 0.f, s1 = 0.f, s2 = 0.f, s3 = 0.f,
              s4 = 0.f, s5 = 0.f, s6 = 0.f, s7 = 0.f;
        int p = 0;
        for (; p + 8 <= j; p += 8) {
            s0 += L[i][p + 0] * L[j][p + 0];
            s1 += L[i][p + 1] * L[j][p + 1];
            s2 += L[i][p + 2] * L[j][p + 2];
            s3 += L[i][p + 3] * L[j][p + 3];
            s4 += L[i][p + 4] * L[j][p + 4];
            s5 += L[i][p + 5] * L[j][p + 5];
            s6 += L[i][p + 6] * L[j][p + 6];
            s7 += L[i][p + 7] * L[j][p + 7];
        }
        for (; p < j; ++p) s0 += L[i][p] * L[j][p];
        s -= ((s0 + s1) + (s2 + s3)) + ((s4 + s5) + (s6 + s7));
        const float dj = sqrtf(__shfl(s, j));
        const float lij = (i == j) ? dj : ((i > j) ? s / dj : 0.0f);
        __syncthreads();
        L[i][j] = lij;
        __syncthreads();
    }

    // W = L^{-1}: lane c computes column c (depends only on earlier rows of
    // the same column -> no cross-lane deps).
    {
        const int c = i;
        for (int r = 0; r < GMM_D; ++r) {
            float val;
            if (r < c) {
                val = 0.0f;
            } else {
                float s = (r == c) ? 1.0f : 0.0f;
                float s0 = 0.f, s1 = 0.f, s2 = 0.f, s3 = 0.f;
                int j = c;
                for (; j + 4 <= r; j += 4) {
                    s0 -= L[r][j + 0] * Ws[j + 0][c];
                    s1 -= L[r][j + 1] * Ws[j + 1][c];
                    s2 -= L[r][j + 2] * Ws[j + 2][c];
                    s3 -= L[r][j + 3] * Ws[j + 3][c];
                }
                for (; j < r; ++j) s0 -= L[r][j] * Ws[j][c];
                s += ((s0 + s1) + (s2 + s3));
                val = s / L[r][r];
            }
            Ws[r][c] = val;
        }
    }
    __syncthreads();

    // t_i = (W mu)_i  (lane i reads row i)
    float ti = 0.0f;
    for (int j = 0; j <= i; ++j) ti += Ws[i][j] * mus[k * GMM_D + j];
    tv[k * GMM_D + i] = ti;

    // COLUMN-major packed-triangular store: column c at offset
    // cb(c) = 64c - c(c-1)/2 holding rows c..63. Lane i owns column i.
    const int cb = GMM_D * i - (i * (i - 1)) / 2;
    for (int r = i; r < GMM_D; ++r)
        Wp[k * GMM_TRI + cb + (r - i)] = Ws[r][i];

    // c_k = log pi_k - sum(log L_ii) - 0.5*D*log(2*pi)
    float ll = logf(L[i][i]);
    for (int off = 32; off > 0; off >>= 1) ll += __shfl_down(ll, off);
    if (i == 0)
        cc[k] = logf(pi[k]) - ll - 0.5f * 64.0f * 1.8378770664093453f;
}

// ---------------------------------------------------------------------------
// E-step: block = 256 threads = 4 waves over the SAME 64 points; wave w
// computes components 4w..4w+3 (wave-uniform k -> s_load W). Column-major:
// z[64] accumulators live in VGPRs; x read from LDS once per column.
// ---------------------------------------------------------------------------
template <int J>
__device__ __forceinline__ void gmm_col(const float* __restrict__ xl,
                                        const float* __restrict__ Wk,
                                        float (&z)[GMM_D])
{
    const float xj = xl[J];  // ds_read_b32, immediate offset
    constexpr int base = GMM_D * J - (J * (J - 1)) / 2;
    #pragma unroll
    for (int i = J; i < GMM_D; ++i)
        z[i] = fmaf(Wk[base + (i - J)], xj, z[i]);
}

template <int... Js>
__device__ __forceinline__ void gmm_all(const float* __restrict__ xl,
                                        const float* __restrict__ Wk,
                                        float (&z)[GMM_D],
                                        std::integer_sequence<int, Js...>)
{
    (gmm_col<Js>(xl, Wk, z), ...);
}

__global__ __launch_bounds__(256) void gmm_estep_kernel(
    const float* __restrict__ X, const float* __restrict__ Wp,
    const float* __restrict__ tv, const float* __restrict__ cc,
    float* __restrict__ out, int N)
{
    __shared__ float xs[64 * 65];  // [point][dim], stride 65: (lane+j)%32 banks
    __shared__ float lg[64 * 17];  // [point][comp], stride 17

    // --- stage X tile: thread t loads point t/4, quarter t%4 (16 floats) ---
    {
        const int p = threadIdx.x >> 2;
        const int q = threadIdx.x & 3;
        const int np = blockIdx.x * 64 + p;
        if (np < N) {
            const float4* src =
                reinterpret_cast<const float4*>(X + (size_t)np * GMM_D) + q * 4;
            #pragma unroll
            for (int u = 0; u < 4; ++u) {
                const float4 v = src[u];
                const int o = p * 65 + q * 16 + u * 4;
                xs[o + 0] = v.x; xs[o + 1] = v.y;
                xs[o + 2] = v.z; xs[o + 3] = v.w;
            }
        }
    }
    __syncthreads();

    const int lane = threadIdx.x & 63;
    const int wave = __builtin_amdgcn_readfirstlane(threadIdx.x >> 6);
    const int n = blockIdx.x * 64 + lane;
    const float* xl = &xs[lane * 65];

    if (n < N) {
        #pragma unroll 1  // body = 2080 FMAs; keep rolled over the 4 comps
        for (int kk = 0; kk < 4; ++kk) {
            const int k = wave * 4 + kk;            // wave-uniform
            const float* Wk = Wp + k * GMM_TRI;     // -> s_load stream
            const float* tk = tv + k * GMM_D;

            float z[GMM_D];
            #pragma unroll
            for (int i = 0; i < GMM_D; ++i) z[i] = -tk[i];

            gmm_all(xl, Wk, z, std::make_integer_sequence<int, GMM_D>{});

            float m0 = 0.f, m1 = 0.f, m2 = 0.f, m3 = 0.f;
            #pragma unroll
            for (int i = 0; i < GMM_D; i += 4) {
                m0 = fmaf(z[i + 0], z[i + 0], m0);
                m1 = fmaf(z[i + 1], z[i + 1], m1);
                m2 = fmaf(z[i + 2], z[i + 2], m2);
                m3 = fmaf(z[i + 3], z[i + 3], m3);
            }
            lg[lane * 17 + k] = cc[k] - 0.5f * ((m0 + m1) + (m2 + m3));
        }
    }
    __syncthreads();

    // softmax: first wave, one thread per point; 4 contiguous float4 stores.
    if (threadIdx.x < 64) {
        const int p = threadIdx.x;
        const int np = blockIdx.x * 64 + p;
        if (np < N) {
            const float* row = &lg[p * 17];
            float m = row[0];
            #pragma unroll
            for (int j = 1; j < GMM_K; ++j) m = fmaxf(m, row[j]);
            float e[GMM_K];
            float s = 0.0f;
            #pragma unroll
            for (int j = 0; j < GMM_K; ++j) { e[j] = __expf(row[j] - m); s += e[j]; }
            const float inv = 1.0f / s;
            float4* op = reinterpret_cast<float4*>(out + (size_t)np * GMM_K);
            #pragma unroll
            for (int q = 0; q < 4; ++q) {
                float4 v;
                v.x = e[4 * q + 0] * inv;
                v.y = e[4 * q + 1] * inv;
                v.z = e[4 * q + 2] * inv;
                v.w = e[4 * q + 3] * inv;
                op[q] = v;
            }
        }
    }
}

// ---------------------------------------------------------------------------
extern "C" void kernel_launch(void* const* d_in, const int* in_sizes, int n_in,
                              void* d_out, int out_size, void* d_ws, size_t ws_size,
                              hipStream_t stream)
{
    const float* X    = (const float*)d_in[0];
    const float* pi   = (const float*)d_in[1];
    const float* mus  = (const float*)d_in[2];
    const float* covs = (const float*)d_in[3];
    float* out = (float*)d_out;

    const int N = in_sizes[0] / GMM_D;

    // workspace: packed W [K*2080] | t [K*64] | c [K]  (~137 KB)
    float* Wp = (float*)d_ws;
    float* tv = Wp + GMM_K * GMM_TRI;
    float* cc = tv + GMM_K * GMM_D;

    gmm_precompute_kernel<<<dim3(GMM_K), dim3(64), 0, stream>>>(pi, mus, covs, Wp, tv, cc);

    const int blocks = (N + 63) / 64;  // 200000/64 = 3125 exactly
    gmm_estep_kernel<<<dim3(blocks), dim3(256), 0, stream>>>(X, Wp, tv, cc, out, N);
}

// Round 5
// 251.247 us; speedup vs baseline: 4.8210x; 4.8210x over previous
//
#include <hip/hip_runtime.h>
#include <cstddef>
#include <cstdint>

// GMM E-step: N=200000, K=16, D=64, fp32 in/out.
// R5: MFMA formulation. z_k = W_k x - t_k computed as 3-pass f16 hi/lo split
// GEMM (Whi*xhi + Whi*xlo + Wlo*xhi) on v_mfma_f32_16x16x32_f16; maha=|z|^2
// reduced in-register. R4's fp32-VALU path measured 12.6 TF effective
// (scalar-feed bound); MFMA floor for 78.6 GFLOP is ~38us.
// W is pre-swizzled into A-fragment order by the precompute kernel.

#define GMM_D 64
#define GMM_K 16

typedef _Float16 half8 __attribute__((ext_vector_type(8)));
typedef float f32x4 __attribute__((ext_vector_type(4)));

// ws layout (bytes): WA [16 comps][16 frags][64 lanes][8 f16] = 262144
//                    tv [16][64] f32 = 4096 ; cc [16] f32
#define WA_BYTES (GMM_K * 16 * 64 * 8 * 2)

// ---------------------------------------------------------------------------
// Precompute: one block (1 wave) per component.
// Right-looking Cholesky (rank-1 updates, no dot products) + R4-proven
// triangular inverse + t, c_k, and the f16 hi/lo A-fragment swizzle of W.
// ---------------------------------------------------------------------------
__global__ __launch_bounds__(64) void gmm_precompute_kernel(
    const float* __restrict__ pi, const float* __restrict__ mus,
    const float* __restrict__ covs, _Float16* __restrict__ WA,
    float* __restrict__ tv, float* __restrict__ cc)
{
    const int k = blockIdx.x;
    const int i = threadIdx.x;  // lane: row (Cholesky) / column (inverse)

    __shared__ float A_[GMM_D][GMM_D + 1];
    __shared__ float Ws[GMM_D][GMM_D + 1];
    __shared__ float colj[GMM_D];

    for (int j = 0; j < GMM_D; ++j) A_[i][j] = covs[k * 4096 + i * 64 + j];
    __syncthreads();

    // Right-looking Cholesky: per column j, O(1) per lane to form the column,
    // then a parallel rank-1 update of the trailing submatrix.
    for (int j = 0; j < GMM_D; ++j) {
        const float dj = sqrtf(A_[j][j]);
        float lij;
        if (i > j)       lij = A_[i][j] / dj;
        else if (i == j) lij = dj;
        else             lij = 0.0f;
        __syncthreads();          // reads of column j done before overwrite
        A_[i][j] = lij;           // finalize L column j in place
        colj[i]  = lij;
        __syncthreads();
        // A[i][p] -= L[i][j] * L[p][j]  for p > j  (rows i<=j: lij pattern is
        // harmless — row j's upper part is never read again)
        int p = j + 1;
        for (; p + 4 <= GMM_D; p += 4) {
            A_[i][p + 0] -= lij * colj[p + 0];
            A_[i][p + 1] -= lij * colj[p + 1];
            A_[i][p + 2] -= lij * colj[p + 2];
            A_[i][p + 3] -= lij * colj[p + 3];
        }
        for (; p < GMM_D; ++p) A_[i][p] -= lij * colj[p];
        __syncthreads();
    }

    // W = L^{-1}: lane c computes column c (forward substitution). R4-proven.
    {
        const int c = i;
        for (int r = 0; r < GMM_D; ++r) {
            float val;
            if (r < c) {
                val = 0.0f;
            } else {
                float s = (r == c) ? 1.0f : 0.0f;
                float s0 = 0.f, s1 = 0.f, s2 = 0.f, s3 = 0.f;
                int j = c;
                for (; j + 4 <= r; j += 4) {
                    s0 -= A_[r][j + 0] * Ws[j + 0][c];
                    s1 -= A_[r][j + 1] * Ws[j + 1][c];
                    s2 -= A_[r][j + 2] * Ws[j + 2][c];
                    s3 -= A_[r][j + 3] * Ws[j + 3][c];
                }
                for (; j < r; ++j) s0 -= A_[r][j] * Ws[j][c];
                s += (s0 + s1) + (s2 + s3);
                val = s / A_[r][r];
            }
            Ws[r][c] = val;
        }
    }
    __syncthreads();

    // t_i = (W mu)_i
    float ti = 0.0f;
    for (int j = 0; j <= i; ++j) ti += Ws[i][j] * mus[k * GMM_D + j];
    tv[k * GMM_D + i] = ti;

    // A-fragment swizzle of W, f16 hi/lo. Fragment (mt, s):
    //   lane L element j  =  Wsel[row = mt*16 + (L&15)][dim = (s&1)*32 + (L>>4)*8 + j]
    //   s in {0,1}: hi ;  s in {2,3}: lo
    // stored at WA + ((k*16 + mt*4 + s)*64 + L)*8  (16B per lane, coalesced)
    {
        const int lr = i & 15;
        const int q  = i >> 4;
        for (int mt = 0; mt < 4; ++mt) {
            for (int s = 0; s < 4; ++s) {
                const int row = mt * 16 + lr;
                const int db  = (s & 1) * 32 + q * 8;
                half8 hv;
                #pragma unroll
                for (int u = 0; u < 8; ++u) {
                    const float v = Ws[row][db + u];
                    _Float16 h = (_Float16)v;
                    if (s >= 2) h = (_Float16)(v - (float)h);
                    hv[u] = h;
                }
                *(half8*)(WA + ((size_t)((k * 16 + mt * 4 + s) * 64) + i) * 8) = hv;
            }
        }
    }

    // c_k = log pi_k - sum(log L_ii) - 0.5*D*log(2*pi)
    float ll = logf(A_[i][i]);
    for (int off = 32; off > 0; off >>= 1) ll += __shfl_down(ll, off);
    if (i == 0)
        cc[k] = logf(pi[k]) - ll - 0.5f * 64.0f * 1.8378770664093453f;
}

// ---------------------------------------------------------------------------
// E-step: block = 256 threads = 4 waves, 64 points. Wave w owns comps
// 4w..4w+3. Per (comp, ntile of 16 pts): 4 Mtiles x 6 MFMAs (16x16x32 f16),
// C preloaded with -t, maha reduced in-register + 2 shfl_xor.
// ---------------------------------------------------------------------------
__global__ __launch_bounds__(256) void gmm_estep_kernel(
    const float* __restrict__ X, const _Float16* __restrict__ WA,
    const float* __restrict__ tv, const float* __restrict__ cc,
    float* __restrict__ out, int N)
{
    // xs row (per point): [hi 0..63 | lo 0..63 | pad 8] f16 = 136 (272 B, 16B-aligned)
    __shared__ _Float16 xs[64 * 136];
    __shared__ float lg[64 * 17];

    const int tid = threadIdx.x;

    // ---- stage X -> f16 hi/lo in LDS. thread t: point t/4, dims (t%4)*16.. ----
    {
        const int p = tid >> 2, qq = tid & 3;
        const int np = blockIdx.x * 64 + p;
        if (np < N) {
            const float4* src = reinterpret_cast<const float4*>(X + (size_t)np * GMM_D) + qq * 4;
            float vv[16];
            #pragma unroll
            for (int u = 0; u < 4; ++u) {
                const float4 v = src[u];
                vv[4 * u + 0] = v.x; vv[4 * u + 1] = v.y;
                vv[4 * u + 2] = v.z; vv[4 * u + 3] = v.w;
            }
            half8 h0, h1, l0, l1;
            #pragma unroll
            for (int u = 0; u < 8; ++u) {
                const _Float16 a = (_Float16)vv[u];
                const _Float16 b = (_Float16)vv[u + 8];
                h0[u] = a; l0[u] = (_Float16)(vv[u] - (float)a);
                h1[u] = b; l1[u] = (_Float16)(vv[u + 8] - (float)b);
            }
            _Float16* row = xs + p * 136;
            *(half8*)(row + qq * 16)      = h0;
            *(half8*)(row + qq * 16 + 8)  = h1;
            *(half8*)(row + 64 + qq * 16)     = l0;
            *(half8*)(row + 64 + qq * 16 + 8) = l1;
        }
    }
    __syncthreads();

    const int lane = tid & 63;
    const int wave = __builtin_amdgcn_readfirstlane(tid >> 6);
    const int pt = lane & 15;
    const int q  = lane >> 4;

    #pragma unroll 1
    for (int kk = 0; kk < 4; ++kk) {
        const int k = wave * 4 + kk;  // wave-uniform

        // A fragments for this comp: 16 x dwordx4, coalesced, L2-resident.
        half8 af[4][4];
        const _Float16* wab = WA + (size_t)k * 8192 + lane * 8;
        #pragma unroll
        for (int mt = 0; mt < 4; ++mt)
            #pragma unroll
            for (int s = 0; s < 4; ++s)
                af[mt][s] = *(const half8*)(wab + (mt * 4 + s) * 512);

        #pragma unroll 1
        for (int nt = 0; nt < 4; ++nt) {
            const _Float16* xrow = xs + (nt * 16 + pt) * 136 + q * 8;
            const half8 bh0 = *(const half8*)(xrow);        // hi dims 0..31
            const half8 bh1 = *(const half8*)(xrow + 32);   // hi dims 32..63
            const half8 bl0 = *(const half8*)(xrow + 64);   // lo dims 0..31
            const half8 bl1 = *(const half8*)(xrow + 96);   // lo dims 32..63

            float mahaP = 0.0f;
            #pragma unroll
            for (int mt = 0; mt < 4; ++mt) {
                const f32x4 t4 = *(const f32x4*)(tv + k * 64 + mt * 16 + q * 4);
                f32x4 c = -t4;  // C init = -t  (rows quad*4+reg of this Mtile)
                c = __builtin_amdgcn_mfma_f32_16x16x32_f16(af[mt][0], bh0, c, 0, 0, 0);
                c = __builtin_amdgcn_mfma_f32_16x16x32_f16(af[mt][1], bh1, c, 0, 0, 0);
                c = __builtin_amdgcn_mfma_f32_16x16x32_f16(af[mt][0], bl0, c, 0, 0, 0);
                c = __builtin_amdgcn_mfma_f32_16x16x32_f16(af[mt][1], bl1, c, 0, 0, 0);
                c = __builtin_amdgcn_mfma_f32_16x16x32_f16(af[mt][2], bh0, c, 0, 0, 0);
                c = __builtin_amdgcn_mfma_f32_16x16x32_f16(af[mt][3], bh1, c, 0, 0, 0);
                mahaP += c[0] * c[0] + c[1] * c[1] + c[2] * c[2] + c[3] * c[3];
            }
            // sum over the 4 quads (same pt lives in lanes pt, pt+16, pt+32, pt+48)
            mahaP += __shfl_xor(mahaP, 16);
            mahaP += __shfl_xor(mahaP, 32);
            if (q == 0 && (blockIdx.x * 64 + nt * 16 + pt) < N)
                lg[(nt * 16 + pt) * 17 + k] = cc[k] - 0.5f * mahaP;
        }
    }
    __syncthreads();

    // softmax: 4 threads/point, each writes one float4 (contiguous 4 KB/block).
    {
        const int p = tid >> 2, qq = tid & 3;
        const int np = blockIdx.x * 64 + p;
        if (np < N) {
            const float* row = &lg[p * 17];
            float m = row[0];
            #pragma unroll
            for (int j = 1; j < GMM_K; ++j) m = fmaxf(m, row[j]);
            float e[GMM_K];
            float s = 0.0f;
            #pragma unroll
            for (int j = 0; j < GMM_K; ++j) { e[j] = __expf(row[j] - m); s += e[j]; }
            const float inv = 1.0f / s;
            float4 v;
            v.x = e[qq * 4 + 0] * inv;
            v.y = e[qq * 4 + 1] * inv;
            v.z = e[qq * 4 + 2] * inv;
            v.w = e[qq * 4 + 3] * inv;
            reinterpret_cast<float4*>(out + (size_t)np * GMM_K)[qq] = v;
        }
    }
}

// ---------------------------------------------------------------------------
extern "C" void kernel_launch(void* const* d_in, const int* in_sizes, int n_in,
                              void* d_out, int out_size, void* d_ws, size_t ws_size,
                              hipStream_t stream)
{
    const float* X    = (const float*)d_in[0];
    const float* pi   = (const float*)d_in[1];
    const float* mus  = (const float*)d_in[2];
    const float* covs = (const float*)d_in[3];
    float* out = (float*)d_out;

    const int N = in_sizes[0] / GMM_D;

    _Float16* WA = (_Float16*)d_ws;
    float* tv = (float*)((char*)d_ws + WA_BYTES);
    float* cc = tv + GMM_K * GMM_D;

    gmm_precompute_kernel<<<dim3(GMM_K), dim3(64), 0, stream>>>(pi, mus, covs, WA, tv, cc);

    const int blocks = (N + 63) / 64;  // 200000/64 = 3125 exactly
    gmm_estep_kernel<<<dim3(blocks), dim3(256), 0, stream>>>(X, WA, tv, cc, out, N);
}

// Round 6
// 225.341 us; speedup vs baseline: 5.3753x; 1.1150x over previous
//
#include <hip/hip_runtime.h>
#include <cstddef>
#include <cstdint>

// GMM E-step: N=200000, K=16, D=64, fp32 in/out.
// R6: precompute rewritten for parallelism (was 112us = 45% of total at
// 0.33% VALUBusy: serial dependent-LDS chains + uncoalesced covs load).
// Now 256 thr/block: coalesced load, right-looking Cholesky with parallel
// rank-1 updates, right-looking forward-substitution inverse (parallel row
// updates), parallel swizzle. Estep (MFMA f16 hi/lo, verified R5) kept,
// with the nt-invariant t4 accumulator-init loads hoisted.

#define GMM_D 64
#define GMM_K 16

typedef _Float16 half8 __attribute__((ext_vector_type(8)));
typedef float f32x4 __attribute__((ext_vector_type(4)));

// ws: WA [16 comps][16 frags][64 lanes][8 f16] = 262144 B, then tv, cc (f32)
#define WA_BYTES (GMM_K * 16 * 64 * 8 * 2)

// ---------------------------------------------------------------------------
// Precompute: one block (256 threads) per component.
// ---------------------------------------------------------------------------
__global__ __launch_bounds__(256) void gmm_precompute_kernel(
    const float* __restrict__ pi, const float* __restrict__ mus,
    const float* __restrict__ covs, _Float16* __restrict__ WA,
    float* __restrict__ tv, float* __restrict__ cc)
{
    const int k = blockIdx.x;
    const int t = threadIdx.x;

    __shared__ float A_[GMM_D][GMM_D + 1];  // Sigma -> L (cols finalized in place)
    __shared__ float Wv[GMM_D][GMM_D + 1];  // I -> L^{-1}
    __shared__ float cj[GMM_D];

    // coalesced Sigma load: 1024 float4, thread t takes i4 = rnd*256 + t
    {
        const float4* src = reinterpret_cast<const float4*>(covs + (size_t)k * 4096);
        #pragma unroll
        for (int rnd = 0; rnd < 4; ++rnd) {
            const int i4 = rnd * 256 + t;
            const float4 v = src[i4];
            const int r = i4 >> 4, c = (i4 & 15) * 4;
            A_[r][c + 0] = v.x; A_[r][c + 1] = v.y;
            A_[r][c + 2] = v.z; A_[r][c + 3] = v.w;
        }
    }
    // W := I
    #pragma unroll
    for (int rnd = 0; rnd < 16; ++rnd) {
        const int idx = rnd * 256 + t;
        const int r = idx >> 6, c = idx & 63;
        Wv[r][c] = (r == c) ? 1.0f : 0.0f;
    }
    __syncthreads();

    const int ur = t >> 2;  // update row (4 threads per row)
    const int uq = t & 3;   // col stride phase

    // ---- Cholesky, right-looking: col j by wave 0, rank-1 update by all ----
    for (int j = 0; j < GMM_D; ++j) {
        if (t < 64) {
            const int r = t;
            const float pivot = A_[j][j];   // one wave: read precedes the write below
            const float dj = sqrtf(pivot);
            float val;
            if (r == j)      val = dj;
            else if (r > j)  val = A_[r][j] / dj;
            else             val = 0.0f;
            A_[r][j] = val;
            cj[r] = val;
        }
        __syncthreads();
        if (ur > j) {
            const float cr = cj[ur];
            for (int p = j + 1 + uq; p <= ur; p += 4)   // lower triangle only
                A_[ur][p] -= cr * cj[p];
        }
        __syncthreads();
    }

    // ---- W = L^{-1}: scale row j (wave 0), update rows r>j (all threads) ----
    for (int j = 0; j < GMM_D; ++j) {
        if (t < 64) {
            Wv[j][t] *= 1.0f / A_[j][j];    // cols > j are 0, harmless
        }
        __syncthreads();
        if (ur > j) {
            const float lrj = A_[ur][j];
            for (int c = uq; c <= j; c += 4)  // row j nonzeros are c <= j
                Wv[ur][c] -= lrj * Wv[j][c];
        }
        __syncthreads();
    }

    // ---- t = W mu (wave 0, 4 partial sums) ----
    if (t < 64) {
        const float* mk = mus + k * GMM_D;
        float s0 = 0.f, s1 = 0.f, s2 = 0.f, s3 = 0.f;
        for (int j = 0; j < GMM_D; j += 4) {
            s0 += Wv[t][j + 0] * mk[j + 0];
            s1 += Wv[t][j + 1] * mk[j + 1];
            s2 += Wv[t][j + 2] * mk[j + 2];
            s3 += Wv[t][j + 3] * mk[j + 3];
        }
        tv[k * GMM_D + t] = (s0 + s1) + (s2 + s3);
    }

    // ---- swizzle W -> f16 hi/lo A-fragments (all 256 threads) ----
    // frag f = mt*4+s: lane L elem j = W[mt*16 + (L&15)][(s&1)*32 + (L>>4)*8 + j],
    // s in {0,1}: hi ; {2,3}: lo. Store 16B/lane, coalesced.
    {
        const int lane6 = t & 63;
        const int fh = t >> 6;
        const int lr = lane6 & 15, q = lane6 >> 4;
        #pragma unroll
        for (int rnd = 0; rnd < 4; ++rnd) {
            const int f = rnd * 4 + fh;
            const int mt = f >> 2, s = f & 3;
            const int row = mt * 16 + lr;
            const int db = (s & 1) * 32 + q * 8;
            half8 hv;
            #pragma unroll
            for (int u = 0; u < 8; ++u) {
                const float v = Wv[row][db + u];
                _Float16 h = (_Float16)v;
                if (s >= 2) h = (_Float16)(v - (float)h);
                hv[u] = h;
            }
            *(half8*)(WA + ((size_t)((k * 16 + f) * 64) + lane6) * 8) = hv;
        }
    }

    // ---- c_k = log pi_k - sum(log L_ii) - 0.5*D*log(2*pi) (wave 0) ----
    if (t < 64) {
        float ll = logf(A_[t][t]);
        #pragma unroll
        for (int off = 32; off > 0; off >>= 1) ll += __shfl_down(ll, off);
        if (t == 0)
            cc[k] = logf(pi[k]) - ll - 0.5f * 64.0f * 1.8378770664093453f;
    }
}

// ---------------------------------------------------------------------------
// E-step (R5-verified): block = 4 waves, 64 points; wave w owns comps
// 4w..4w+3. Per (comp, ntile): 4 Mtiles x 6 MFMA 16x16x32 f16 (hi*hi + hi*lo
// + lo*hi), C preloaded with -t, maha reduced in-register + 2 shfl_xor.
// ---------------------------------------------------------------------------
__global__ __launch_bounds__(256) void gmm_estep_kernel(
    const float* __restrict__ X, const _Float16* __restrict__ WA,
    const float* __restrict__ tv, const float* __restrict__ cc,
    float* __restrict__ out, int N)
{
    // xs row (per point): [hi 0..63 | lo 0..63 | pad 8] f16 = 136 (272 B)
    __shared__ _Float16 xs[64 * 136];
    __shared__ float lg[64 * 17];

    const int tid = threadIdx.x;

    // ---- stage X -> f16 hi/lo in LDS: thread t: point t/4, dims (t%4)*16.. ----
    {
        const int p = tid >> 2, qq = tid & 3;
        const int np = blockIdx.x * 64 + p;
        if (np < N) {
            const float4* src = reinterpret_cast<const float4*>(X + (size_t)np * GMM_D) + qq * 4;
            float vv[16];
            #pragma unroll
            for (int u = 0; u < 4; ++u) {
                const float4 v = src[u];
                vv[4 * u + 0] = v.x; vv[4 * u + 1] = v.y;
                vv[4 * u + 2] = v.z; vv[4 * u + 3] = v.w;
            }
            half8 h0, h1, l0, l1;
            #pragma unroll
            for (int u = 0; u < 8; ++u) {
                const _Float16 a = (_Float16)vv[u];
                const _Float16 b = (_Float16)vv[u + 8];
                h0[u] = a; l0[u] = (_Float16)(vv[u] - (float)a);
                h1[u] = b; l1[u] = (_Float16)(vv[u + 8] - (float)b);
            }
            _Float16* row = xs + p * 136;
            *(half8*)(row + qq * 16)          = h0;
            *(half8*)(row + qq * 16 + 8)      = h1;
            *(half8*)(row + 64 + qq * 16)     = l0;
            *(half8*)(row + 64 + qq * 16 + 8) = l1;
        }
    }
    __syncthreads();

    const int lane = tid & 63;
    const int wave = __builtin_amdgcn_readfirstlane(tid >> 6);
    const int pt = lane & 15;
    const int q  = lane >> 4;

    #pragma unroll 1
    for (int kk = 0; kk < 4; ++kk) {
        const int k = wave * 4 + kk;  // wave-uniform

        // A fragments: 16 x global_load_dwordx4, coalesced, L2-resident.
        half8 af[4][4];
        const _Float16* wab = WA + (size_t)k * 8192 + lane * 8;
        #pragma unroll
        for (int mt = 0; mt < 4; ++mt)
            #pragma unroll
            for (int s = 0; s < 4; ++s)
                af[mt][s] = *(const half8*)(wab + (mt * 4 + s) * 512);

        // nt-invariant accumulator inits: -t rows for each Mtile
        f32x4 tk4[4];
        #pragma unroll
        for (int mt = 0; mt < 4; ++mt)
            tk4[mt] = *(const f32x4*)(tv + k * 64 + mt * 16 + q * 4);

        #pragma unroll 1
        for (int nt = 0; nt < 4; ++nt) {
            const _Float16* xrow = xs + (nt * 16 + pt) * 136 + q * 8;
            const half8 bh0 = *(const half8*)(xrow);        // hi dims 0..31
            const half8 bh1 = *(const half8*)(xrow + 32);   // hi dims 32..63
            const half8 bl0 = *(const half8*)(xrow + 64);   // lo dims 0..31
            const half8 bl1 = *(const half8*)(xrow + 96);   // lo dims 32..63

            float mahaP = 0.0f;
            #pragma unroll
            for (int mt = 0; mt < 4; ++mt) {
                f32x4 c = -tk4[mt];
                c = __builtin_amdgcn_mfma_f32_16x16x32_f16(af[mt][0], bh0, c, 0, 0, 0);
                c = __builtin_amdgcn_mfma_f32_16x16x32_f16(af[mt][1], bh1, c, 0, 0, 0);
                c = __builtin_amdgcn_mfma_f32_16x16x32_f16(af[mt][0], bl0, c, 0, 0, 0);
                c = __builtin_amdgcn_mfma_f32_16x16x32_f16(af[mt][1], bl1, c, 0, 0, 0);
                c = __builtin_amdgcn_mfma_f32_16x16x32_f16(af[mt][2], bh0, c, 0, 0, 0);
                c = __builtin_amdgcn_mfma_f32_16x16x32_f16(af[mt][3], bh1, c, 0, 0, 0);
                mahaP += c[0] * c[0] + c[1] * c[1] + c[2] * c[2] + c[3] * c[3];
            }
            mahaP += __shfl_xor(mahaP, 16);
            mahaP += __shfl_xor(mahaP, 32);
            if (q == 0 && (blockIdx.x * 64 + nt * 16 + pt) < N)
                lg[(nt * 16 + pt) * 17 + k] = cc[k] - 0.5f * mahaP;
        }
    }
    __syncthreads();

    // softmax: 4 threads/point, one float4 each (contiguous stores)
    {
        const int p = tid >> 2, qq = tid & 3;
        const int np = blockIdx.x * 64 + p;
        if (np < N) {
            const float* row = &lg[p * 17];
            float m = row[0];
            #pragma unroll
            for (int j = 1; j < GMM_K; ++j) m = fmaxf(m, row[j]);
            float e[GMM_K];
            float s = 0.0f;
            #pragma unroll
            for (int j = 0; j < GMM_K; ++j) { e[j] = __expf(row[j] - m); s += e[j]; }
            const float inv = 1.0f / s;
            float4 v;
            v.x = e[qq * 4 + 0] * inv;
            v.y = e[qq * 4 + 1] * inv;
            v.z = e[qq * 4 + 2] * inv;
            v.w = e[qq * 4 + 3] * inv;
            reinterpret_cast<float4*>(out + (size_t)np * GMM_K)[qq] = v;
        }
    }
}

// ---------------------------------------------------------------------------
extern "C" void kernel_launch(void* const* d_in, const int* in_sizes, int n_in,
                              void* d_out, int out_size, void* d_ws, size_t ws_size,
                              hipStream_t stream)
{
    const float* X    = (const float*)d_in[0];
    const float* pi   = (const float*)d_in[1];
    const float* mus  = (const float*)d_in[2];
    const float* covs = (const float*)d_in[3];
    float* out = (float*)d_out;

    const int N = in_sizes[0] / GMM_D;

    _Float16* WA = (_Float16*)d_ws;
    float* tv = (float*)((char*)d_ws + WA_BYTES);
    float* cc = tv + GMM_K * GMM_D;

    gmm_precompute_kernel<<<dim3(GMM_K), dim3(256), 0, stream>>>(pi, mus, covs, WA, tv, cc);

    const int blocks = (N + 63) / 64;  // 200000/64 = 3125 exactly
    gmm_estep_kernel<<<dim3(blocks), dim3(256), 0, stream>>>(X, WA, tv, cc, out, N);
}